// Round 13
// baseline (261.436 us; speedup 1.0000x reference)
//
#include <hip/hip_runtime.h>

typedef unsigned short u16;
typedef unsigned int   u32;
typedef __attribute__((ext_vector_type(8))) short bf16x8;
typedef __attribute__((ext_vector_type(4))) float f32x4;
typedef __attribute__((ext_vector_type(2))) float f32x2;

#define NFEAT  256
#define NBATCH 8192
#define BT     128   // batch tile per iteration (4 waves)
#define NBT    (NBATCH / BT)   // 64
#define ITERS  8     // bt-iterations per persistent block -> grid 2048

__device__ __forceinline__ u16 f2bf(float f) {
    u32 u = __builtin_bit_cast(u32, f);
    return (u16)((u + 0x7FFFu + ((u >> 16) & 1u)) >> 16);
}
__device__ __forceinline__ u32 cvtpk(float a, float b) {
    u32 r;
    asm("v_cvt_pk_bf16_f32 %0, %1, %2" : "=v"(r) : "v"(a), "v"(b));
    return r;   // lo16 = bf16(a), hi16 = bf16(b), RNE
}
__device__ __forceinline__ f32x4 mfma16(bf16x8 a, bf16x8 b, f32x4 c) {
    return __builtin_amdgcn_mfma_f32_16x16x32_bf16(a, b, c, 0, 0, 0);
}
__device__ __forceinline__ bf16x8 frag_word0(u32 word0) {
    union { bf16x8 v; u32 w[4]; } u;
    u.w[0] = word0; u.w[1] = 0; u.w[2] = 0; u.w[3] = 0;
    return u.v;
}
// XOR swizzle, 256B rows (R8-proven; R10's rotate variant measured 2x worse)
__device__ __forceinline__ char* swz(char* base, int b, int col2) {
    return base + b * 256 + (col2 ^ ((b & 15) << 4));
}
__device__ __forceinline__ const char* swz(const char* base, int b, int col2) {
    return base + b * 256 + (col2 ^ ((b & 15) << 4));
}
// bias + relu + pack, vector add first (v_pk_add_f32 eligible)
__device__ __forceinline__ uint2 relu_pk4(f32x4 v, f32x4 bs) {
    f32x4 s = v + bs;
    return make_uint2(cvtpk(fmaxf(s[0], 0.f), fmaxf(s[1], 0.f)),
                      cvtpk(fmaxf(s[2], 0.f), fmaxf(s[3], 0.f)));
}
// barrier that drains ONLY LDS counters: global stores/loads stay in flight
// (cross-wave deps in nam_main are LDS-only; __syncthreads would force
// vmcnt(0) and stall on L3's global stores every iteration)
__device__ __forceinline__ void barrier_lgkm() {
    asm volatile("s_waitcnt lgkmcnt(0)" ::: "memory");
    __builtin_amdgcn_s_barrier();
    asm volatile("" ::: "memory");   // fence: no LDS op hoisted above barrier
}

// ---------------------------------------------------------------------------
// prep: w0[f,o] = g_in[f,o] * sign(v_in[f,o,0])
// ---------------------------------------------------------------------------
__global__ void prep_w0(const float* __restrict__ v_in, const float* __restrict__ g_in,
                        u16* __restrict__ w0) {
    int i = blockIdx.x * blockDim.x + threadIdx.x;   // < 32768
    float v = v_in[i];
    float g = g_in[i];
    w0[i] = f2bf(v >= 0.f ? g : -g);
}

// ---------------------------------------------------------------------------
// prep: weight-normalize v_h0/v_h1/v_out rows -> bf16.  One wave per row.
// ---------------------------------------------------------------------------
__global__ void prep_norm(const float* __restrict__ v_h0, const float* __restrict__ g_h0,
                          const float* __restrict__ v_h1, const float* __restrict__ g_h1,
                          const float* __restrict__ v_out, const float* __restrict__ g_out,
                          u16* __restrict__ w1, u16* __restrict__ w2, u16* __restrict__ w3) {
    const int wave = (blockIdx.x * blockDim.x + threadIdx.x) >> 6;
    const int lane = threadIdx.x & 63;
    if (wave < 32768 + 16384) {
        const float* src; u16* dst; float g;
        if (wave < 32768) {
            src = v_h0 + (size_t)wave * 128; dst = w1 + (size_t)wave * 128; g = g_h0[wave];
        } else {
            int r = wave - 32768;
            src = v_h1 + (size_t)r * 128; dst = w2 + (size_t)r * 128; g = g_h1[r];
        }
        f32x2 v = *(const f32x2*)(src + lane * 2);
        float ss = v[0] * v[0] + v[1] * v[1];
        #pragma unroll
        for (int off = 32; off; off >>= 1) ss += __shfl_xor(ss, off);
        float s = g * rsqrtf(ss);
        *(u32*)(dst + lane * 2) = cvtpk(v[0] * s, v[1] * s);
    } else {
        int r = wave - 49152;   // < 4096
        const float* src = v_out + (size_t)r * 64;
        float v = src[lane];
        float ss = v * v;
        #pragma unroll
        for (int off = 32; off; off >>= 1) ss += __shfl_xor(ss, off);
        float s = g_out[r] * rsqrtf(ss);
        w3[(size_t)r * 64 + lane] = f2bf(v * s);
    }
}

// ---------------------------------------------------------------------------
// prep: x_t[f][b] = bf16( tab[b,0,f] * (1 - tab[b,1,f]) )   (64x64 LDS transpose)
// ---------------------------------------------------------------------------
__global__ void prep_x(const float* __restrict__ tab, u16* __restrict__ x_t) {
    __shared__ u16 tile[64][65];
    const int bb = (blockIdx.x % (NBATCH / 64)) * 64;
    const int ff = (blockIdx.x / (NBATCH / 64)) * 64;
    const int tr = threadIdx.x >> 6;    // 0..3
    const int tc = threadIdx.x & 63;
    #pragma unroll
    for (int i = 0; i < 16; i++) {
        int b = bb + tr + i * 4;
        float val  = tab[(size_t)b * 512 + ff + tc];
        float miss = tab[(size_t)b * 512 + 256 + ff + tc];
        tile[tr + i * 4][tc] = f2bf(val * (1.f - miss));
    }
    __syncthreads();
    #pragma unroll
    for (int i = 0; i < 16; i++) {
        int fr = tr + i * 4;
        x_t[(size_t)(ff + fr) * NBATCH + bb + tc] = tile[tc][fr];
    }
}

// ---------------------------------------------------------------------------
// logits[b][j] = bias[j] + sum_f outputs[b][f][j]
// ---------------------------------------------------------------------------
__global__ void reduce_logits(const float* __restrict__ outputs,
                              const float* __restrict__ bias,
                              float* __restrict__ logits) {
    const int b = blockIdx.x * 4 + (threadIdx.x >> 6);
    const int lane = threadIdx.x & 63;
    const int j4 = lane & 3;     // output quad
    const int fo = lane >> 2;    // feature offset 0..15
    const float* base = outputs + (size_t)b * (NFEAT * 16);
    f32x4 acc = {};
    #pragma unroll
    for (int it = 0; it < 16; it++) {
        f32x4 v = *(const f32x4*)(base + (fo + it * 16) * 16 + j4 * 4);
        acc[0] += v[0]; acc[1] += v[1]; acc[2] += v[2]; acc[3] += v[3];
    }
    #pragma unroll
    for (int off = 4; off < 64; off <<= 1) {
        acc[0] += __shfl_xor(acc[0], off);
        acc[1] += __shfl_xor(acc[1], off);
        acc[2] += __shfl_xor(acc[2], off);
        acc[3] += __shfl_xor(acc[3], off);
    }
    if (lane < 4) {
        f32x4 bs = *(const f32x4*)(bias + lane * 4);
        acc[0] += bs[0]; acc[1] += bs[1]; acc[2] += bs[2]; acc[3] += bs[3];
        *(f32x4*)(logits + b * 16 + lane * 4) = acc;
    }
}

// ---------------------------------------------------------------------------
// main: persistent-f blocks, 256 thr = 4 waves, BT=128.  R11 base plus:
// (1) lgkmcnt-only raw barriers (global stores fly across iters),
// (2) L2 re-split by b (each wave full o=64 for its own 32 batches) so L3
//     reads only own-wave LDS rows -> L2->L3 needs NO barrier: 3 barriers/iter.
// L0 -> hA, L1 -> hB, [L2 -> hA + L3 -> global] fused.
// XOR-swizzled LDS, weights/biases persistent.  64KB LDS -> 2 blocks/CU.
// ---------------------------------------------------------------------------
__global__ __launch_bounds__(256, 2) void nam_main(
    const u16* __restrict__ x_t, const u16* __restrict__ w0g,
    const u16* __restrict__ w1g, const u16* __restrict__ w2g, const u16* __restrict__ w3g,
    const float* __restrict__ b_in, const float* __restrict__ b_h0, const float* __restrict__ b_h1,
    float* __restrict__ outputs)
{
    __shared__ u16 hA[BT * 128];   // h0: 128 rows x 256B, later h2 (cols 0..127B)
    __shared__ u16 hB[BT * 128];   // h1: 128 rows x 256B

    const int bid   = blockIdx.x;
    const int f     = (bid & 7) * 32 + ((bid >> 3) & 31);  // XCD-contiguous features
    const int chunk = bid >> 8;                            // 0..7
    const int t  = threadIdx.x;
    const int w  = t >> 6;          // 0..3
    const int wo = w >> 1;          // o-half (L0/L1)
    const int wb = w & 1;           // b-half (L0/L1/L2-read-src is b-split anyway)
    const int lane = t & 63;
    const int lo = lane & 15;
    const int hi = lane >> 4;

    // ---- persistent per-feature state ----
    bf16x8 a0f[4];                  // L0 A-frags {w0, bf16(b_in)}, hoisted
    #pragma unroll
    for (int m = 0; m < 4; m++) {
        const int o = f * 128 + wo * 64 + m * 16 + lo;
        float bi = b_in[o];
        u32 pk = (u32)w0g[o] | (cvtpk(bi, bi) << 16);
        a0f[m] = frag_word0(hi == 0 ? pk : 0u);
    }
    bf16x8 w1f[4][4];   // o = wo*64 + m*16 + lo, k = ks*32 + hi*8
    {
        const u16* base = w1g + ((size_t)(f * 128 + wo * 64 + lo)) * 128 + hi * 8;
        #pragma unroll
        for (int m = 0; m < 4; m++)
            #pragma unroll
            for (int ks = 0; ks < 4; ks++)
                w1f[m][ks] = *(const bf16x8*)(base + m * 2048 + ks * 32);
    }
    bf16x8 w2f[4][4];   // FULL W2 per wave: o = m*16 + lo (b-split L2)
    {
        const u16* base = w2g + ((size_t)(f * 64 + lo)) * 128 + hi * 8;
        #pragma unroll
        for (int m = 0; m < 4; m++)
            #pragma unroll
            for (int ks = 0; ks < 4; ks++)
                w2f[m][ks] = *(const bf16x8*)(base + m * 2048 + ks * 32);
    }
    bf16x8 w3f[2];      // o = lo (16 rows)
    {
        const u16* base = w3g + ((size_t)(f * 16 + lo)) * 64 + hi * 8;
        #pragma unroll
        for (int ks = 0; ks < 2; ks++)
            w3f[ks] = *(const bf16x8*)(base + ks * 32);
    }
    f32x4 bs1[4];   // b_h0 for ob = wo*64 + m*16 + hi*4
    #pragma unroll
    for (int m = 0; m < 4; m++)
        bs1[m] = *(const f32x4*)(b_h0 + f * 128 + wo * 64 + m * 16 + hi * 4);
    f32x4 bs2[4];   // b_h1 full-o: ob = m*16 + hi*4
    #pragma unroll
    for (int m = 0; m < 4; m++)
        bs2[m] = *(const f32x4*)(b_h1 + f * 64 + m * 16 + hi * 4);

    const u16* xbase = x_t + (size_t)f * NBATCH;

    // prime xw for first tile
    u32 xw[4];
    {
        const int bt0 = chunk * ITERS;
        #pragma unroll
        for (int n = 0; n < 4; n++)
            xw[n] = (u32)xbase[bt0 * BT + wb * 64 + n * 16 + lo];
    }

    for (int it = 0; it < ITERS; it++) {
        const int bt = chunk * ITERS + it;

        barrier_lgkm();   // all waves' L2/L3 LDS reads of hA done (stores may fly)

        // ---------- layer 0 (rank-2 MFMA): h0[o][b] = relu(w0[o]*x[b]+b_in[o])
        {
            bf16x8 bm[4];
            #pragma unroll
            for (int n = 0; n < 4; n++)
                bm[n] = frag_word0(hi == 0 ? (xw[n] | 0x3F800000u) : 0u);
            #pragma unroll
            for (int m = 0; m < 4; m++) {
                #pragma unroll
                for (int n = 0; n < 4; n++) {
                    f32x4 d = mfma16(a0f[m], bm[n], f32x4{});
                    const int b = wb * 64 + n * 16 + lo;
                    const int col2 = (wo * 64 + m * 16 + hi * 4) * 2;
                    *(uint2*)swz((char*)hA, b, col2) =
                        make_uint2(cvtpk(fmaxf(0.f, d[0]), fmaxf(0.f, d[1])),
                                   cvtpk(fmaxf(0.f, d[2]), fmaxf(0.f, d[3])));
                }
            }
        }
        barrier_lgkm();

        // ---------- layer 1: h1 = relu(W1 (128x128) . h0^T + b_h0) ----------
        {
            // prefetch next tile's x under the MFMA phase
            if (it + 1 < ITERS) {
                #pragma unroll
                for (int n = 0; n < 4; n++)
                    xw[n] = (u32)xbase[(bt + 1) * BT + wb * 64 + n * 16 + lo];
            }
            f32x4 acc[4][4] = {};
            #pragma unroll
            for (int ks = 0; ks < 4; ks++) {
                bf16x8 bm[4];
                #pragma unroll
                for (int n = 0; n < 4; n++) {
                    const int b = wb * 64 + n * 16 + lo;
                    bm[n] = *(const bf16x8*)swz((const char*)hA, b, ks * 64 + hi * 16);
                }
                __builtin_amdgcn_s_setprio(1);
                #pragma unroll
                for (int m = 0; m < 4; m++)
                    #pragma unroll
                    for (int n = 0; n < 4; n++)
                        acc[m][n] = mfma16(w1f[m][ks], bm[n], acc[m][n]);
                __builtin_amdgcn_s_setprio(0);
            }
            #pragma unroll
            for (int m = 0; m < 4; m++) {
                const int col2 = (wo * 64 + m * 16 + hi * 4) * 2;
                #pragma unroll
                for (int n = 0; n < 4; n++) {
                    const int b = wb * 64 + n * 16 + lo;
                    *(uint2*)swz((char*)hB, b, col2) = relu_pk4(acc[m][n], bs1[m]);
                }
            }
        }
        barrier_lgkm();

        // ---------- layer 2 (b-split): h2[b][o], o=0..63 full, b = w*32..+32
        // each wave writes ONLY rows b in [w*32, w*32+32) of hA -> its own L3
        // reads need no barrier (intra-wave lgkmcnt ordering suffices)
        {
            f32x4 acc[4][2] = {};
            #pragma unroll
            for (int ks = 0; ks < 4; ks++) {
                bf16x8 bm[2];
                #pragma unroll
                for (int n = 0; n < 2; n++) {
                    const int b = w * 32 + n * 16 + lo;
                    bm[n] = *(const bf16x8*)swz((const char*)hB, b, ks * 64 + hi * 16);
                }
                __builtin_amdgcn_s_setprio(1);
                #pragma unroll
                for (int m = 0; m < 4; m++)
                    #pragma unroll
                    for (int n = 0; n < 2; n++)
                        acc[m][n] = mfma16(w2f[m][ks], bm[n], acc[m][n]);
                __builtin_amdgcn_s_setprio(0);
            }
            #pragma unroll
            for (int m = 0; m < 4; m++) {
                const int col2 = (m * 16 + hi * 4) * 2;
                #pragma unroll
                for (int n = 0; n < 2; n++) {
                    const int b = w * 32 + n * 16 + lo;
                    *(uint2*)swz((char*)hA, b, col2) = relu_pk4(acc[m][n], bs2[m]);
                }
            }
        }
        // NO barrier: L3 reads only rows this wave just wrote

        // ---------- layer 3: out = W3 (16x64) . h2^T ------------------------
        {
            f32x4 acc[2] = {};
            #pragma unroll
            for (int ks = 0; ks < 2; ks++) {
                #pragma unroll
                for (int n = 0; n < 2; n++) {
                    const int b = w * 32 + n * 16 + lo;
                    bf16x8 bm = *(const bf16x8*)swz((const char*)hA, b, ks * 64 + hi * 16);
                    acc[n] = mfma16(w3f[ks], bm, acc[n]);
                }
            }
            #pragma unroll
            for (int n = 0; n < 2; n++) {
                const int gb = bt * BT + w * 32 + n * 16 + lo;   // global batch row
                float* op = outputs + ((size_t)gb * NFEAT + f) * 16 + hi * 4;
                *(f32x4*)op = acc[n];
            }
        }
    }
}

// ---------------------------------------------------------------------------
extern "C" void kernel_launch(void* const* d_in, const int* in_sizes, int n_in,
                              void* d_out, int out_size, void* d_ws, size_t ws_size,
                              hipStream_t stream) {
    const float* tab   = (const float*)d_in[0];
    const float* v_in  = (const float*)d_in[1];
    const float* g_in  = (const float*)d_in[2];
    const float* b_in  = (const float*)d_in[3];
    const float* v_h0  = (const float*)d_in[4];
    const float* g_h0  = (const float*)d_in[5];
    const float* b_h0  = (const float*)d_in[6];
    const float* v_h1  = (const float*)d_in[7];
    const float* g_h1  = (const float*)d_in[8];
    const float* b_h1  = (const float*)d_in[9];
    const float* v_out = (const float*)d_in[10];
    const float* g_out = (const float*)d_in[11];
    const float* bias  = (const float*)d_in[12];

    char* ws = (char*)d_ws;
    u16* w0  = (u16*)(ws);                         //  32768 * 2
    u16* w1  = (u16*)(ws + 65536);                 // 4194304 * 2
    u16* w2  = (u16*)(ws + 65536 + 8388608);       // 2097152 * 2
    u16* w3  = (u16*)(ws + 12648448);              //  262144 * 2
    u16* x_t = (u16*)(ws + 13172736);              // 2097152 * 2  (end ~17.4MB)

    float* logits  = (float*)d_out;
    float* outputs = (float*)d_out + (size_t)NBATCH * 16;

    hipLaunchKernelGGL(prep_w0,   dim3(128),   dim3(256), 0, stream, v_in, g_in, w0);
    hipLaunchKernelGGL(prep_norm, dim3(13312), dim3(256), 0, stream,
                       v_h0, g_h0, v_h1, g_h1, v_out, g_out, w1, w2, w3);
    hipLaunchKernelGGL(prep_x,    dim3(512),   dim3(256), 0, stream, tab, x_t);
    hipLaunchKernelGGL(nam_main,  dim3(NFEAT * NBT / ITERS), dim3(256), 0, stream,
                       x_t, w0, w1, w2, w3, b_in, b_h0, b_h1, outputs);
    hipLaunchKernelGGL(reduce_logits, dim3(NBATCH / 4), dim3(256), 0, stream,
                       outputs, bias, logits);
}

// Round 14
// 181.804 us; speedup vs baseline: 1.4380x; 1.4380x over previous
//
#include <hip/hip_runtime.h>

typedef unsigned short u16;
typedef unsigned int   u32;
typedef __attribute__((ext_vector_type(8))) short bf16x8;
typedef __attribute__((ext_vector_type(4))) float f32x4;
typedef __attribute__((ext_vector_type(2))) float f32x2;

#define NFEAT  256
#define NBATCH 8192
#define BT     128   // batch tile per iteration (4 waves: 2 o-halves x 2 b-halves)
#define NBT    (NBATCH / BT)   // 64
#define ITERS  8     // bt-iterations per persistent block -> grid 2048

__device__ __forceinline__ u16 f2bf(float f) {
    u32 u = __builtin_bit_cast(u32, f);
    return (u16)((u + 0x7FFFu + ((u >> 16) & 1u)) >> 16);
}
__device__ __forceinline__ u32 cvtpk(float a, float b) {
    u32 r;
    asm("v_cvt_pk_bf16_f32 %0, %1, %2" : "=v"(r) : "v"(a), "v"(b));
    return r;   // lo16 = bf16(a), hi16 = bf16(b), RNE
}
__device__ __forceinline__ f32x4 mfma16(bf16x8 a, bf16x8 b, f32x4 c) {
    return __builtin_amdgcn_mfma_f32_16x16x32_bf16(a, b, c, 0, 0, 0);
}
__device__ __forceinline__ bf16x8 frag_word0(u32 word0) {
    union { bf16x8 v; u32 w[4]; } u;
    u.w[0] = word0; u.w[1] = 0; u.w[2] = 0; u.w[3] = 0;
    return u.v;
}
// XOR swizzle, 256B rows (R8-proven; R10's rotate variant measured 2x worse)
__device__ __forceinline__ char* swz(char* base, int b, int col2) {
    return base + b * 256 + (col2 ^ ((b & 15) << 4));
}
__device__ __forceinline__ const char* swz(const char* base, int b, int col2) {
    return base + b * 256 + (col2 ^ ((b & 15) << 4));
}
// bias + relu + pack, vector add first (v_pk_add_f32 eligible)
__device__ __forceinline__ uint2 relu_pk4(f32x4 v, f32x4 bs) {
    f32x4 s = v + bs;
    return make_uint2(cvtpk(fmaxf(s[0], 0.f), fmaxf(s[1], 0.f)),
                      cvtpk(fmaxf(s[2], 0.f), fmaxf(s[3], 0.f)));
}
// barrier draining ONLY LDS counters (cross-wave deps here are LDS-only):
// L3's global stores + xw prefetch loads stay in flight across iterations.
// (__syncthreads would emit s_waitcnt vmcnt(0) -> per-iter HBM-latency stall.
// Race-freedom verified: R13 used this barrier and passed absmax.)
__device__ __forceinline__ void barrier_lgkm() {
    asm volatile("s_waitcnt lgkmcnt(0)" ::: "memory");
    __builtin_amdgcn_s_barrier();
    asm volatile("" ::: "memory");   // no LDS op hoisted above the barrier
}

// ---------------------------------------------------------------------------
// prep: w0[f,o] = g_in[f,o] * sign(v_in[f,o,0])
// ---------------------------------------------------------------------------
__global__ void prep_w0(const float* __restrict__ v_in, const float* __restrict__ g_in,
                        u16* __restrict__ w0) {
    int i = blockIdx.x * blockDim.x + threadIdx.x;   // < 32768
    float v = v_in[i];
    float g = g_in[i];
    w0[i] = f2bf(v >= 0.f ? g : -g);
}

// ---------------------------------------------------------------------------
// prep: weight-normalize v_h0/v_h1/v_out rows -> bf16.  One wave per row.
// ---------------------------------------------------------------------------
__global__ void prep_norm(const float* __restrict__ v_h0, const float* __restrict__ g_h0,
                          const float* __restrict__ v_h1, const float* __restrict__ g_h1,
                          const float* __restrict__ v_out, const float* __restrict__ g_out,
                          u16* __restrict__ w1, u16* __restrict__ w2, u16* __restrict__ w3) {
    const int wave = (blockIdx.x * blockDim.x + threadIdx.x) >> 6;
    const int lane = threadIdx.x & 63;
    if (wave < 32768 + 16384) {
        const float* src; u16* dst; float g;
        if (wave < 32768) {
            src = v_h0 + (size_t)wave * 128; dst = w1 + (size_t)wave * 128; g = g_h0[wave];
        } else {
            int r = wave - 32768;
            src = v_h1 + (size_t)r * 128; dst = w2 + (size_t)r * 128; g = g_h1[r];
        }
        f32x2 v = *(const f32x2*)(src + lane * 2);
        float ss = v[0] * v[0] + v[1] * v[1];
        #pragma unroll
        for (int off = 32; off; off >>= 1) ss += __shfl_xor(ss, off);
        float s = g * rsqrtf(ss);
        *(u32*)(dst + lane * 2) = cvtpk(v[0] * s, v[1] * s);
    } else {
        int r = wave - 49152;   // < 4096
        const float* src = v_out + (size_t)r * 64;
        float v = src[lane];
        float ss = v * v;
        #pragma unroll
        for (int off = 32; off; off >>= 1) ss += __shfl_xor(ss, off);
        float s = g_out[r] * rsqrtf(ss);
        w3[(size_t)r * 64 + lane] = f2bf(v * s);
    }
}

// ---------------------------------------------------------------------------
// prep: x_t[f][b] = bf16( tab[b,0,f] * (1 - tab[b,1,f]) )   (64x64 LDS transpose)
// ---------------------------------------------------------------------------
__global__ void prep_x(const float* __restrict__ tab, u16* __restrict__ x_t) {
    __shared__ u16 tile[64][65];
    const int bb = (blockIdx.x % (NBATCH / 64)) * 64;
    const int ff = (blockIdx.x / (NBATCH / 64)) * 64;
    const int tr = threadIdx.x >> 6;    // 0..3
    const int tc = threadIdx.x & 63;
    #pragma unroll
    for (int i = 0; i < 16; i++) {
        int b = bb + tr + i * 4;
        float val  = tab[(size_t)b * 512 + ff + tc];
        float miss = tab[(size_t)b * 512 + 256 + ff + tc];
        tile[tr + i * 4][tc] = f2bf(val * (1.f - miss));
    }
    __syncthreads();
    #pragma unroll
    for (int i = 0; i < 16; i++) {
        int fr = tr + i * 4;
        x_t[(size_t)(ff + fr) * NBATCH + bb + tc] = tile[tc][fr];
    }
}

// ---------------------------------------------------------------------------
// logits[b][j] = bias[j] + sum_f outputs[b][f][j]
// ---------------------------------------------------------------------------
__global__ void reduce_logits(const float* __restrict__ outputs,
                              const float* __restrict__ bias,
                              float* __restrict__ logits) {
    const int b = blockIdx.x * 4 + (threadIdx.x >> 6);
    const int lane = threadIdx.x & 63;
    const int j4 = lane & 3;     // output quad
    const int fo = lane >> 2;    // feature offset 0..15
    const float* base = outputs + (size_t)b * (NFEAT * 16);
    f32x4 acc = {};
    #pragma unroll
    for (int it = 0; it < 16; it++) {
        f32x4 v = *(const f32x4*)(base + (fo + it * 16) * 16 + j4 * 4);
        acc[0] += v[0]; acc[1] += v[1]; acc[2] += v[2]; acc[3] += v[3];
    }
    #pragma unroll
    for (int off = 4; off < 64; off <<= 1) {
        acc[0] += __shfl_xor(acc[0], off);
        acc[1] += __shfl_xor(acc[1], off);
        acc[2] += __shfl_xor(acc[2], off);
        acc[3] += __shfl_xor(acc[3], off);
    }
    if (lane < 4) {
        f32x4 bs = *(const f32x4*)(bias + lane * 4);
        acc[0] += bs[0]; acc[1] += bs[1]; acc[2] += bs[2]; acc[3] += bs[3];
        *(f32x4*)(logits + b * 16 + lane * 4) = acc;
    }
}

// ---------------------------------------------------------------------------
// main: EXACT R11 structure (measured best, no spill) with ONE change:
// lgkm-only barriers so global stores/loads fly across iterations.
// persistent-f blocks, 256 thr = 4 waves (wo x wb = 2x2), BT=128.
// L0 -> hA, L1 -> hB, L2 -> hA, L3 -> global, 4 barriers/iter.
// XOR-swizzled LDS, vectorized epilogues, hoisted L0 A-frags, xw prefetch.
// All weights/biases persistent in registers.  64KB LDS -> 2 blocks/CU.
// ---------------------------------------------------------------------------
__global__ __launch_bounds__(256, 2) void nam_main(
    const u16* __restrict__ x_t, const u16* __restrict__ w0g,
    const u16* __restrict__ w1g, const u16* __restrict__ w2g, const u16* __restrict__ w3g,
    const float* __restrict__ b_in, const float* __restrict__ b_h0, const float* __restrict__ b_h1,
    float* __restrict__ outputs)
{
    __shared__ u16 hA[BT * 128];   // h0: 128 rows x 256B, later h2 (cols 0..127B)
    __shared__ u16 hB[BT * 128];   // h1: 128 rows x 256B

    const int bid   = blockIdx.x;
    const int f     = (bid & 7) * 32 + ((bid >> 3) & 31);  // XCD-contiguous features
    const int chunk = bid >> 8;                            // 0..7
    const int t  = threadIdx.x;
    const int w  = t >> 6;          // 0..3
    const int wo = w >> 1;          // o-half
    const int wb = w & 1;           // b-half
    const int lane = t & 63;
    const int lo = lane & 15;
    const int hi = lane >> 4;

    // ---- persistent per-feature state ----
    bf16x8 a0f[4];                  // L0 A-frags {w0, bf16(b_in)}, hoisted
    #pragma unroll
    for (int m = 0; m < 4; m++) {
        const int o = f * 128 + wo * 64 + m * 16 + lo;
        float bi = b_in[o];
        u32 pk = (u32)w0g[o] | (cvtpk(bi, bi) << 16);
        a0f[m] = frag_word0(hi == 0 ? pk : 0u);
    }
    bf16x8 w1f[4][4];   // o = wo*64 + m*16 + lo, k = ks*32 + hi*8
    {
        const u16* base = w1g + ((size_t)(f * 128 + wo * 64 + lo)) * 128 + hi * 8;
        #pragma unroll
        for (int m = 0; m < 4; m++)
            #pragma unroll
            for (int ks = 0; ks < 4; ks++)
                w1f[m][ks] = *(const bf16x8*)(base + m * 2048 + ks * 32);
    }
    bf16x8 w2f[2][4];   // o = wo*32 + m*16 + lo
    {
        const u16* base = w2g + ((size_t)(f * 64 + wo * 32 + lo)) * 128 + hi * 8;
        #pragma unroll
        for (int m = 0; m < 2; m++)
            #pragma unroll
            for (int ks = 0; ks < 4; ks++)
                w2f[m][ks] = *(const bf16x8*)(base + m * 2048 + ks * 32);
    }
    bf16x8 w3f[2];      // o = lo (16 rows)
    {
        const u16* base = w3g + ((size_t)(f * 16 + lo)) * 64 + hi * 8;
        #pragma unroll
        for (int ks = 0; ks < 2; ks++)
            w3f[ks] = *(const bf16x8*)(base + ks * 32);
    }
    f32x4 bs1[4];   // b_h0 for ob = wo*64 + m*16 + hi*4
    #pragma unroll
    for (int m = 0; m < 4; m++)
        bs1[m] = *(const f32x4*)(b_h0 + f * 128 + wo * 64 + m * 16 + hi * 4);
    f32x4 bs2[2];   // b_h1 for ob = wo*32 + m*16 + hi*4
    #pragma unroll
    for (int m = 0; m < 2; m++)
        bs2[m] = *(const f32x4*)(b_h1 + f * 64 + wo * 32 + m * 16 + hi * 4);

    const u16* xbase = x_t + (size_t)f * NBATCH;

    // prime xw for first tile
    u32 xw[4];
    {
        const int bt0 = chunk * ITERS;
        #pragma unroll
        for (int n = 0; n < 4; n++)
            xw[n] = (u32)xbase[bt0 * BT + wb * 64 + n * 16 + lo];
    }

    for (int it = 0; it < ITERS; it++) {
        const int bt = chunk * ITERS + it;

        barrier_lgkm();   // prev iter's L3 LDS reads of hA done (stores fly)

        // ---------- layer 0 (rank-2 MFMA): h0[o][b] = relu(w0[o]*x[b]+b_in[o])
        {
            bf16x8 bm[4];
            #pragma unroll
            for (int n = 0; n < 4; n++)
                bm[n] = frag_word0(hi == 0 ? (xw[n] | 0x3F800000u) : 0u);
            #pragma unroll
            for (int m = 0; m < 4; m++) {
                #pragma unroll
                for (int n = 0; n < 4; n++) {
                    f32x4 d = mfma16(a0f[m], bm[n], f32x4{});
                    const int b = wb * 64 + n * 16 + lo;
                    const int col2 = (wo * 64 + m * 16 + hi * 4) * 2;
                    *(uint2*)swz((char*)hA, b, col2) =
                        make_uint2(cvtpk(fmaxf(0.f, d[0]), fmaxf(0.f, d[1])),
                                   cvtpk(fmaxf(0.f, d[2]), fmaxf(0.f, d[3])));
                }
            }
        }
        barrier_lgkm();

        // ---------- layer 1: h1 = relu(W1 (128x128) . h0^T + b_h0) ----------
        {
            // prefetch next tile's x under the MFMA phase
            if (it + 1 < ITERS) {
                #pragma unroll
                for (int n = 0; n < 4; n++)
                    xw[n] = (u32)xbase[(bt + 1) * BT + wb * 64 + n * 16 + lo];
            }
            f32x4 acc[4][4] = {};
            #pragma unroll
            for (int ks = 0; ks < 4; ks++) {
                bf16x8 bm[4];
                #pragma unroll
                for (int n = 0; n < 4; n++) {
                    const int b = wb * 64 + n * 16 + lo;
                    bm[n] = *(const bf16x8*)swz((const char*)hA, b, ks * 64 + hi * 16);
                }
                __builtin_amdgcn_s_setprio(1);
                #pragma unroll
                for (int m = 0; m < 4; m++)
                    #pragma unroll
                    for (int n = 0; n < 4; n++)
                        acc[m][n] = mfma16(w1f[m][ks], bm[n], acc[m][n]);
                __builtin_amdgcn_s_setprio(0);
            }
            #pragma unroll
            for (int m = 0; m < 4; m++) {
                const int col2 = (wo * 64 + m * 16 + hi * 4) * 2;
                #pragma unroll
                for (int n = 0; n < 4; n++) {
                    const int b = wb * 64 + n * 16 + lo;
                    *(uint2*)swz((char*)hB, b, col2) = relu_pk4(acc[m][n], bs1[m]);
                }
            }
        }
        barrier_lgkm();

        // ---------- layer 2: h2 = relu(W2 (64x128) . h1^T + b_h1) -----------
        // h2 -> hA rows (cols 0..127B of 256B rows)
        {
            f32x4 acc[2][4] = {};
            #pragma unroll
            for (int ks = 0; ks < 4; ks++) {
                bf16x8 bm[4];
                #pragma unroll
                for (int n = 0; n < 4; n++) {
                    const int b = wb * 64 + n * 16 + lo;
                    bm[n] = *(const bf16x8*)swz((const char*)hB, b, ks * 64 + hi * 16);
                }
                __builtin_amdgcn_s_setprio(1);
                #pragma unroll
                for (int m = 0; m < 2; m++)
                    #pragma unroll
                    for (int n = 0; n < 4; n++)
                        acc[m][n] = mfma16(w2f[m][ks], bm[n], acc[m][n]);
                __builtin_amdgcn_s_setprio(0);
            }
            #pragma unroll
            for (int m = 0; m < 2; m++) {
                const int col2 = (wo * 32 + m * 16 + hi * 4) * 2;
                #pragma unroll
                for (int n = 0; n < 4; n++) {
                    const int b = wb * 64 + n * 16 + lo;
                    *(uint2*)swz((char*)hA, b, col2) = relu_pk4(acc[m][n], bs2[m]);
                }
            }
        }
        barrier_lgkm();

        // ---------- layer 3: out = W3 (16x64) . h2^T ------------------------
        // 4 waves split b 4-ways: b = w*32 + n*16 + lo, n 0..1
        {
            f32x4 acc[2] = {};
            #pragma unroll
            for (int ks = 0; ks < 2; ks++) {
                #pragma unroll
                for (int n = 0; n < 2; n++) {
                    const int b = w * 32 + n * 16 + lo;
                    bf16x8 bm = *(const bf16x8*)swz((const char*)hA, b, ks * 64 + hi * 16);
                    acc[n] = mfma16(w3f[ks], bm, acc[n]);
                }
            }
            #pragma unroll
            for (int n = 0; n < 2; n++) {
                const int gb = bt * BT + w * 32 + n * 16 + lo;   // global batch row
                float* op = outputs + ((size_t)gb * NFEAT + f) * 16 + hi * 4;
                *(f32x4*)op = acc[n];
            }
        }
    }
}

// ---------------------------------------------------------------------------
extern "C" void kernel_launch(void* const* d_in, const int* in_sizes, int n_in,
                              void* d_out, int out_size, void* d_ws, size_t ws_size,
                              hipStream_t stream) {
    const float* tab   = (const float*)d_in[0];
    const float* v_in  = (const float*)d_in[1];
    const float* g_in  = (const float*)d_in[2];
    const float* b_in  = (const float*)d_in[3];
    const float* v_h0  = (const float*)d_in[4];
    const float* g_h0  = (const float*)d_in[5];
    const float* b_h0  = (const float*)d_in[6];
    const float* v_h1  = (const float*)d_in[7];
    const float* g_h1  = (const float*)d_in[8];
    const float* b_h1  = (const float*)d_in[9];
    const float* v_out = (const float*)d_in[10];
    const float* g_out = (const float*)d_in[11];
    const float* bias  = (const float*)d_in[12];

    char* ws = (char*)d_ws;
    u16* w0  = (u16*)(ws);                         //  32768 * 2
    u16* w1  = (u16*)(ws + 65536);                 // 4194304 * 2
    u16* w2  = (u16*)(ws + 65536 + 8388608);       // 2097152 * 2
    u16* w3  = (u16*)(ws + 12648448);              //  262144 * 2
    u16* x_t = (u16*)(ws + 13172736);              // 2097152 * 2  (end ~17.4MB)

    float* logits  = (float*)d_out;
    float* outputs = (float*)d_out + (size_t)NBATCH * 16;

    hipLaunchKernelGGL(prep_w0,   dim3(128),   dim3(256), 0, stream, v_in, g_in, w0);
    hipLaunchKernelGGL(prep_norm, dim3(13312), dim3(256), 0, stream,
                       v_h0, g_h0, v_h1, g_h1, v_out, g_out, w1, w2, w3);
    hipLaunchKernelGGL(prep_x,    dim3(512),   dim3(256), 0, stream, tab, x_t);
    hipLaunchKernelGGL(nam_main,  dim3(NFEAT * NBT / ITERS), dim3(256), 0, stream,
                       x_t, w0, w1, w2, w3, b_in, b_h0, b_h1, outputs);
    hipLaunchKernelGGL(reduce_logits, dim3(NBATCH / 4), dim3(256), 0, stream,
                       outputs, bias, logits);
}